// Round 9
// baseline (2684.667 us; speedup 1.0000x reference)
//
#include <hip/hip_runtime.h>

typedef __attribute__((ext_vector_type(8))) short bf16x8;
typedef __attribute__((ext_vector_type(4))) float f32x4;

// ---- sizes ----
// B=128, T=256, EMB=512, H=1024, 4H=4096, VOC=32000
// out layout: [128][256][1024] f32, then hT [128][1024], then cT [128][1024]

__device__ __forceinline__ unsigned short f2bf(float f) {
  unsigned int u = __builtin_bit_cast(unsigned int, f);
  u = (u + 0x7FFFu + ((u >> 16) & 1u)) >> 16;  // RNE
  return (unsigned short)u;
}
__device__ __forceinline__ float bf2f(unsigned short s) {
  unsigned int u = ((unsigned int)s) << 16;
  return __builtin_bit_cast(float, u);
}
__device__ __forceinline__ void gload_lds16(const void* g, void* l) {
  __builtin_amdgcn_global_load_lds(
      (const __attribute__((address_space(1))) void*)g,
      (__attribute__((address_space(3))) void*)l, 16, 0, 0);
}
__device__ __forceinline__ float sigm(float x) { return 1.0f / (1.0f + __expf(-x)); }
__device__ __forceinline__ float tanh_f(float x) {
  float e = __expf(2.0f * x);
  return 1.0f - 2.0f / (e + 1.0f);  // saturates correctly, no NaN at +-inf
}

// combine one tagged u64 (two dwords, each (tag<<16)|bf16) -> packed 2xbf16 dword
__device__ __forceinline__ unsigned comb(unsigned long long v) {
  return (unsigned)(v & 0xFFFFull) | (unsigned)((v >> 16) & 0xFFFF0000ull);
}

// ---------------- f32 -> bf16 elementwise (emb table) ----------------
__global__ void cvt_bf16_vec(const float4* __restrict__ in, ushort4* __restrict__ out, int n4) {
  int i = blockIdx.x * blockDim.x + threadIdx.x;
  int stride = gridDim.x * blockDim.x;
  for (; i < n4; i += stride) {
    float4 v = in[i];
    ushort4 o;
    o.x = f2bf(v.x); o.y = f2bf(v.y); o.z = f2bf(v.z); o.w = f2bf(v.w);
    out[i] = o;
  }
}

// ---- transpose f32 [K][N] -> bf16 [N][K]; SWZ: bake 16B-slot XOR swizzle ----
template <int SWZ>
__global__ void transpose_cvt(const float* __restrict__ in, unsigned short* __restrict__ out,
                              int K, int N) {
  __shared__ float tile[64][65];
  int k0 = blockIdx.x * 64, n0 = blockIdx.y * 64;
  int tid = threadIdx.x;
  int c = tid & 63, rq = tid >> 6;
#pragma unroll
  for (int rr = 0; rr < 16; ++rr) {
    int r = rr * 4 + rq;
    tile[r][c] = in[(size_t)(k0 + r) * N + n0 + c];
  }
  __syncthreads();
#pragma unroll
  for (int ww = 0; ww < 16; ++ww) {
    int nl = ww * 4 + rq;
    int n = n0 + nl;
    int kd = c;
    int ksrc;
    if (SWZ) {
      int s = kd >> 3, e = kd & 7;
      ksrc = ((((s ^ (n & 7)) & 7)) << 3) | e;
    } else {
      ksrc = kd;
    }
    out[(size_t)n * K + k0 + kd] = f2bf(tile[ksrc][nl]);
  }
}

// ---------------- pre = gather(emb,x) @ W + b   -> bf16 [32768][4096] ----------------
__global__ __launch_bounds__(256) void pregemm(
    const unsigned short* __restrict__ emb_bf, const int* __restrict__ x,
    const unsigned short* __restrict__ W_sw, const float* __restrict__ bias,
    unsigned short* __restrict__ pre) {
  __shared__ __align__(16) unsigned short A_lds[2][8192];  // 128 rows x 64 k (swizzled slots)
  __shared__ __align__(16) unsigned short B_lds[2][8192];
  int bid = blockIdx.x;
  int mtile = bid >> 5, ntile = bid & 31;  // 256 x 32
  int tid = threadIdx.x, wv = tid >> 6, ln = tid & 63;

  int xrow[4];
#pragma unroll
  for (int i = 0; i < 4; ++i) {
    int chunk = wv * 4 + i;
    int r = chunk * 8 + (ln >> 3);
    xrow[i] = x[mtile * 128 + r];
  }

  auto stage = [&](int buf, int kb) {
    int k0 = kb * 64;
#pragma unroll
    for (int i = 0; i < 4; ++i) {
      int chunk = wv * 4 + i;
      int r = chunk * 8 + (ln >> 3);
      const unsigned short* srcA =
          emb_bf + (size_t)xrow[i] * 512 + k0 + (((ln & 7) ^ (r & 7)) << 3);
      gload_lds16(srcA, &A_lds[buf][chunk * 512]);
      const unsigned short* srcB =
          W_sw + (size_t)(ntile * 128 + r) * 512 + k0 + ((ln & 7) << 3);
      gload_lds16(srcB, &B_lds[buf][chunk * 512]);
    }
  };

  f32x4 acc[4][4];
#pragma unroll
  for (int i = 0; i < 4; ++i)
#pragma unroll
    for (int j = 0; j < 4; ++j) acc[i][j] = (f32x4)0.0f;

  int wm = wv >> 1, wn = wv & 1;
  stage(0, 0);
#pragma unroll 1
  for (int kb = 0; kb < 8; ++kb) {
    __syncthreads();
    if (kb < 7) stage((kb + 1) & 1, kb + 1);
    int buf = kb & 1;
#pragma unroll
    for (int ks = 0; ks < 2; ++ks) {
      bf16x8 a[4], b[4];
#pragma unroll
      for (int f = 0; f < 4; ++f) {
        int r = wm * 64 + f * 16 + (ln & 15);
        int sa = ((ks * 4 + (ln >> 4)) ^ (r & 7)) & 7;
        a[f] = *(const bf16x8*)&A_lds[buf][r * 64 + sa * 8];
        int n = wn * 64 + f * 16 + (ln & 15);
        int sb = ((ks * 4 + (ln >> 4)) ^ (n & 7)) & 7;
        b[f] = *(const bf16x8*)&B_lds[buf][n * 64 + sb * 8];
      }
#pragma unroll
      for (int i = 0; i < 4; ++i)
#pragma unroll
        for (int j = 0; j < 4; ++j)
          acc[i][j] = __builtin_amdgcn_mfma_f32_16x16x32_bf16(a[i], b[j], acc[i][j], 0, 0, 0);
    }
  }
#pragma unroll
  for (int fm = 0; fm < 4; ++fm) {
#pragma unroll
    for (int fn = 0; fn < 4; ++fn) {
      int n = ntile * 128 + wn * 64 + fn * 16 + (ln & 15);
      float bn = bias[n];
      int m0 = mtile * 128 + wm * 64 + fm * 16 + ((ln >> 4) << 2);
#pragma unroll
      for (int i = 0; i < 4; ++i) {
        pre[(size_t)(m0 + i) * 4096 + n] = f2bf(acc[fm][fn][i] + bn);
      }
    }
  }
}

// ---------------- agent-scope init of tagged hbc + flags ----------------
// CRITICAL (r5/r6 lesson): the tagged region must ONLY ever be touched by
// agent-scope ops -- dedicated region, agent-scope init stores.
__global__ void init_htag(unsigned int* hb, unsigned int* flags) {
  int i = blockIdx.x * blockDim.x + threadIdx.x;  // 262144 dwords
  __hip_atomic_store(&hb[i], 0xFFFF0000u, __ATOMIC_RELAXED, __HIP_MEMORY_SCOPE_AGENT);
  if (i < 256)
    __hip_atomic_store(&flags[i], 0u, __ATOMIC_RELAXED, __HIP_MEMORY_SCOPE_AGENT);
}

// ---------------- persistent LSTM recurrence ----------------
// grid 256 = 4 batch-groups (32 rows) x 64 j-slices (16 hidden cols); 512 thr = 8 waves.
// h exchange: tagged words (tag=t)<<16 | bf16(h) in a DEDICATED agent-only region.
// Consume fast path: bounded retry on agent-scope tagged loads; exact tag match ==
// data is h_{t-1} (per-dword self-validating; only the producing step writes that tag
// to that parity slot). Fallback after 64 tries: r7's proven flag poll + reload ->
// liveness guaranteed, cannot hang. Publish: tagged h store (consumer-critical),
// then r7 chain (drain + SYNC2 + per-WG flag) OFF the critical path.
// Overwrite-safety: producer J writes parity slot p at t+2 only after validating all
// tags t+1, incl. consumer X's; X published t+1 only after its MFMA consumed h_t.
// zbuf WAR: gates read zbuf(t) before SYNC2(t); any wave's zbuf write(t+1) is after
// SYNC2(t). Sound with single-parity zbuf.
__global__ __launch_bounds__(512, 2) void lstm_kernel(
    const unsigned short* __restrict__ pre, const unsigned short* __restrict__ U_t,
    unsigned int* __restrict__ hbc, float* __restrict__ out, unsigned int* flags) {
  __shared__ float zbuf[8][32][68];  // [wave slice][row][z-col], padded
  int bid = blockIdx.x;
  int bg = bid >> 6, js = bid & 63;
  int tid = threadIdx.x, wv = tid >> 6, ln = tid & 63;

  // resident B fragments: ub[gate][kk]; col = gate*1024 + js*16 + (ln&15)
  bf16x8 ub[4][4];
#pragma unroll
  for (int f = 0; f < 4; ++f) {
    int col = f * 1024 + js * 16 + (ln & 15);
#pragma unroll
    for (int kk = 0; kk < 4; ++kk) {
      int k = wv * 128 + kk * 32 + ((ln >> 4) << 3);
      ub[f][kk] = *(const bf16x8*)&U_t[(size_t)col * 1024 + k];
    }
  }

  // gate-phase ownership: 512 threads = 32 rows x 16 j
  int row = tid >> 4, j = tid & 15;
  int b = bg * 32 + row;
  int hcol = js * 16 + j;
  float c_state = 0.0f;
  size_t preb = ((size_t)b * 256) * 4096 + (size_t)(js * 16 + j);
  size_t outb = ((size_t)b * 256) * 1024 + (size_t)hcol;
  // per-lane A-operand bases (dword units): rows bg*32+(ln&15), +16; k-slot (ln>>4)*8
  int arow0 = bg * 32 + (ln & 15);
  int arow1 = arow0 + 16;
  int rb0 = arow0 * 1024 + wv * 128 + ((ln >> 4) << 3);  // even -> u64-aligned
  int rb1 = arow1 * 1024 + wv * 128 + ((ln >> 4) << 3);
  unsigned int* mypub = hbc + (size_t)b * 1024 + hcol;            // + parity*131072
  const unsigned int* flp = flags + bg * 64 + (wv << 3) + (ln & 7);  // my 8 producers
  unsigned int* myflag = flags + bg * 64 + js;

  // prefetch pre[t=0]
  float z0n, z1n, z2n, z3n;
  {
    const unsigned short* pp = pre + preb;
    z0n = bf2f(pp[0]); z1n = bf2f(pp[1024]); z2n = bf2f(pp[2048]); z3n = bf2f(pp[3072]);
  }

#pragma unroll 1
  for (int t = 0; t < 256; ++t) {
    int p = t & 1;
    if (t > 0) {
      const unsigned int* hb = hbc + (size_t)(p ^ 1) * 131072;
      const unsigned long long* q0 = (const unsigned long long*)(hb + rb0);
      const unsigned long long* q1 = (const unsigned long long*)(hb + rb1);
      unsigned long long pat = ((unsigned long long)(unsigned)(t - 1) << 16) |
                               ((unsigned long long)(unsigned)(t - 1) << 48);
      unsigned long long v0[16], v1[16];
      auto load_all = [&]() {
#pragma unroll
        for (int kk = 0; kk < 4; ++kk)
#pragma unroll
          for (int i = 0; i < 4; ++i) {
            v0[kk * 4 + i] = __hip_atomic_load(q0 + kk * 16 + i, __ATOMIC_RELAXED,
                                               __HIP_MEMORY_SCOPE_AGENT);
            v1[kk * 4 + i] = __hip_atomic_load(q1 + kk * 16 + i, __ATOMIC_RELAXED,
                                               __HIP_MEMORY_SCOPE_AGENT);
          }
      };
      // fast path: bounded tag-validated retry (1 IF round trip on success)
      bool ok = false;
#pragma unroll 1
      for (int r = 0; r < 64; ++r) {
        load_all();
        unsigned long long bad = 0ull;
#pragma unroll
        for (int i = 0; i < 16; ++i) bad |= (v0[i] ^ pat) | (v1[i] ^ pat);
        if (__all((bad & 0xFFFF0000FFFF0000ull) == 0ull)) { ok = true; break; }
        __builtin_amdgcn_s_sleep(1);
      }
      if (!ok) {
        // fallback (PROVEN r7 chain): flag poll -> reload. Guarantees liveness.
        int guard = 0;
        while (!__all((int)(__hip_atomic_load(flp, __ATOMIC_RELAXED,
                                              __HIP_MEMORY_SCOPE_AGENT) >= (unsigned)t))) {
          if (++guard > 4000000) break;  // fail fast+visibly, never hang
          __builtin_amdgcn_s_sleep(1);
        }
        asm volatile("" ::: "memory");  // no hoisting of reload above the poll
        load_all();
      }
      f32x4 acc[2][4];
#pragma unroll
      for (int m = 0; m < 2; ++m)
#pragma unroll
        for (int f = 0; f < 4; ++f) acc[m][f] = (f32x4)0.0f;
#pragma unroll
      for (int kk = 0; kk < 4; ++kk) {
        union { unsigned d[4]; bf16x8 v; } a0u, a1u;
#pragma unroll
        for (int i = 0; i < 4; ++i) {
          a0u.d[i] = comb(v0[kk * 4 + i]);
          a1u.d[i] = comb(v1[kk * 4 + i]);
        }
#pragma unroll
        for (int f = 0; f < 4; ++f) {
          acc[0][f] = __builtin_amdgcn_mfma_f32_16x16x32_bf16(a0u.v, ub[f][kk], acc[0][f], 0, 0, 0);
          acc[1][f] = __builtin_amdgcn_mfma_f32_16x16x32_bf16(a1u.v, ub[f][kk], acc[1][f], 0, 0, 0);
        }
      }
      // private-slice zbuf writes (2-way bank alias max)
#pragma unroll
      for (int m = 0; m < 2; ++m)
#pragma unroll
        for (int f = 0; f < 4; ++f)
#pragma unroll
          for (int i = 0; i < 4; ++i)
            zbuf[wv][m * 16 + ((ln >> 4) << 2) + i][f * 16 + (ln & 15)] = acc[m][f][i];
      __syncthreads();  // SYNC1
    }
    // gates (Keras order i,f,c,o) from prefetched pre values
    float z0 = z0n, z1 = z1n, z2 = z2n, z3 = z3n;
    if (t > 0) {
      float s0 = 0.f, s1 = 0.f, s2 = 0.f, s3 = 0.f;
#pragma unroll
      for (int s = 0; s < 8; ++s) {
        s0 += zbuf[s][row][j];
        s1 += zbuf[s][row][16 + j];
        s2 += zbuf[s][row][32 + j];
        s3 += zbuf[s][row][48 + j];
      }
      z0 += s0; z1 += s1; z2 += s2; z3 += s3;
    }
    float ig = sigm(z0), fg = sigm(z1), gg = tanh_f(z2), og = sigm(z3);
    c_state = fg * c_state + ig * gg;
    float h = og * tanh_f(c_state);
    // tagged publish FIRST -- this is what consumers' fast path waits on
    unsigned word = ((unsigned)t << 16) | (unsigned)f2bf(h);
    __hip_atomic_store(mypub + (size_t)p * 131072, word, __ATOMIC_RELAXED,
                       __HIP_MEMORY_SCOPE_AGENT);
    if (t == 255) {
      out[outb + (size_t)t * 1024] = h;
      out[33554432 + (size_t)b * 1024 + hcol] = h;
      out[33554432 + 131072 + (size_t)b * 1024 + hcol] = c_state;
    } else {
      // r7 fallback/ordering chain -- OFF the consumer critical path:
      // drain own stores, join WG, tid0 publishes the per-WG flag.
      asm volatile("s_waitcnt vmcnt(0)" ::: "memory");
      __syncthreads();  // SYNC2 (also orders zbuf reads(t) vs writes(t+1))
      if (tid == 0)
        __hip_atomic_store(myflag, (unsigned)(t + 1), __ATOMIC_RELAXED,
                           __HIP_MEMORY_SCOPE_AGENT);
      // bulk out store + next-step prefetch after publish
      out[outb + (size_t)t * 1024] = h;
      const unsigned short* pp = pre + preb + (size_t)(t + 1) * 4096;
      z0n = bf2f(pp[0]); z1n = bf2f(pp[1024]); z2n = bf2f(pp[2048]); z3n = bf2f(pp[3072]);
    }
  }
}

// ---------------- launcher ----------------
extern "C" void kernel_launch(void* const* d_in, const int* in_sizes, int n_in,
                              void* d_out, int out_size, void* d_ws, size_t ws_size,
                              hipStream_t stream) {
  const int*   x    = (const int*)d_in[0];
  // d_in[1] = hidden (ignored by reference module)
  const float* emb  = (const float*)d_in[2];
  const float* W    = (const float*)d_in[3];
  const float* U    = (const float*)d_in[4];
  const float* bias = (const float*)d_in[5];
  float* out = (float*)d_out;

  // workspace layout (bytes). hbc is a DEDICATED agent-only region (r5/r6 lesson:
  // never alias regions previously touched by plain stores/loads).
  const size_t OFS_PRE = 0;                     // 32768*4096*2 = 268435456
  const size_t OFS_EMB = 268435456;             // 32000*512*2  = 32768000
  const size_t OFS_WSW = 301203456;             // 4096*512*2   = 4194304
  const size_t OFS_UT  = 305397760;             // 4096*1024*2  = 8388608
  const size_t OFS_HBC = 313786368;             // 2*128*1024*4 = 1048576 (tagged)
  const size_t OFS_FLG = 314834944;             // 256 * 4B     = 1024
  const size_t WS_NEED = 314835968;
  if (ws_size < WS_NEED) return;  // insufficient scratch -> fail validation visibly

  char* ws = (char*)d_ws;
  unsigned short* pre_p = (unsigned short*)(ws + OFS_PRE);
  unsigned short* emb_p = (unsigned short*)(ws + OFS_EMB);
  unsigned short* wsw_p = (unsigned short*)(ws + OFS_WSW);
  unsigned short* ut_p  = (unsigned short*)(ws + OFS_UT);
  unsigned int*   hbc_p = (unsigned int*)(ws + OFS_HBC);
  unsigned int*   flg_p = (unsigned int*)(ws + OFS_FLG);

  cvt_bf16_vec<<<2048, 256, 0, stream>>>((const float4*)emb, (ushort4*)emb_p, 4096000);
  transpose_cvt<1><<<dim3(8, 64), 256, 0, stream>>>(W, wsw_p, 512, 4096);
  transpose_cvt<0><<<dim3(16, 64), 256, 0, stream>>>(U, ut_p, 1024, 4096);
  init_htag<<<1024, 256, 0, stream>>>(hbc_p, flg_p);
  pregemm<<<8192, 256, 0, stream>>>(emb_p, x, wsw_p, bias, pre_p);

  const unsigned short* pre_c = pre_p;
  const unsigned short* ut_c  = ut_p;
  unsigned int* hbc_v = hbc_p;
  float* out_v = out;
  unsigned int* flg_v = flg_p;
  void* args[] = {(void*)&pre_c, (void*)&ut_c, (void*)&hbc_v, (void*)&out_v, (void*)&flg_v};
  hipLaunchCooperativeKernel((const void*)lstm_kernel, dim3(256), dim3(512), args, 0, stream);
}

// Round 10
// 1798.862 us; speedup vs baseline: 1.4924x; 1.4924x over previous
//
#include <hip/hip_runtime.h>

typedef __attribute__((ext_vector_type(8))) short bf16x8;
typedef __attribute__((ext_vector_type(4))) float f32x4;

// ---- sizes ----
// B=128, T=256, EMB=512, H=1024, 4H=4096, VOC=32000
// out layout: [128][256][1024] f32, then hT [128][1024], then cT [128][1024]

__device__ __forceinline__ unsigned short f2bf(float f) {
  unsigned int u = __builtin_bit_cast(unsigned int, f);
  u = (u + 0x7FFFu + ((u >> 16) & 1u)) >> 16;  // RNE
  return (unsigned short)u;
}
__device__ __forceinline__ float bf2f(unsigned short s) {
  unsigned int u = ((unsigned int)s) << 16;
  return __builtin_bit_cast(float, u);
}
__device__ __forceinline__ void gload_lds16(const void* g, void* l) {
  __builtin_amdgcn_global_load_lds(
      (const __attribute__((address_space(1))) void*)g,
      (__attribute__((address_space(3))) void*)l, 16, 0, 0);
}
__device__ __forceinline__ float sigm(float x) { return 1.0f / (1.0f + __expf(-x)); }
__device__ __forceinline__ float tanh_f(float x) {
  float e = __expf(2.0f * x);
  return 1.0f - 2.0f / (e + 1.0f);  // saturates correctly, no NaN at +-inf
}

// device-coherent (agent-scope) 16B h load as two 8B atomic loads
__device__ __forceinline__ bf16x8 loadh16(const unsigned short* p) {
  unsigned long long* q = (unsigned long long*)p;
  unsigned long long lo = __hip_atomic_load(q, __ATOMIC_RELAXED, __HIP_MEMORY_SCOPE_AGENT);
  unsigned long long hi = __hip_atomic_load(q + 1, __ATOMIC_RELAXED, __HIP_MEMORY_SCOPE_AGENT);
  union { unsigned long long u[2]; bf16x8 v; } c;
  c.u[0] = lo; c.u[1] = hi;
  return c.v;
}

// ---------------- f32 -> bf16 elementwise (emb table) ----------------
__global__ void cvt_bf16_vec(const float4* __restrict__ in, ushort4* __restrict__ out, int n4) {
  int i = blockIdx.x * blockDim.x + threadIdx.x;
  int stride = gridDim.x * blockDim.x;
  for (; i < n4; i += stride) {
    float4 v = in[i];
    ushort4 o;
    o.x = f2bf(v.x); o.y = f2bf(v.y); o.z = f2bf(v.z); o.w = f2bf(v.w);
    out[i] = o;
  }
}

// ---- transpose f32 [K][N] -> bf16 [N][K]; SWZ: bake 16B-slot XOR swizzle ----
template <int SWZ>
__global__ void transpose_cvt(const float* __restrict__ in, unsigned short* __restrict__ out,
                              int K, int N) {
  __shared__ float tile[64][65];
  int k0 = blockIdx.x * 64, n0 = blockIdx.y * 64;
  int tid = threadIdx.x;
  int c = tid & 63, rq = tid >> 6;
#pragma unroll
  for (int rr = 0; rr < 16; ++rr) {
    int r = rr * 4 + rq;
    tile[r][c] = in[(size_t)(k0 + r) * N + n0 + c];
  }
  __syncthreads();
#pragma unroll
  for (int ww = 0; ww < 16; ++ww) {
    int nl = ww * 4 + rq;
    int n = n0 + nl;
    int kd = c;
    int ksrc;
    if (SWZ) {
      int s = kd >> 3, e = kd & 7;
      ksrc = ((((s ^ (n & 7)) & 7)) << 3) | e;
    } else {
      ksrc = kd;
    }
    out[(size_t)n * K + k0 + kd] = f2bf(tile[ksrc][nl]);
  }
}

// ---------------- pre = gather(emb,x) @ W + b   -> bf16 [32768][4096] ----------------
__global__ __launch_bounds__(256) void pregemm(
    const unsigned short* __restrict__ emb_bf, const int* __restrict__ x,
    const unsigned short* __restrict__ W_sw, const float* __restrict__ bias,
    unsigned short* __restrict__ pre) {
  __shared__ __align__(16) unsigned short A_lds[2][8192];  // 128 rows x 64 k (swizzled slots)
  __shared__ __align__(16) unsigned short B_lds[2][8192];
  int bid = blockIdx.x;
  int mtile = bid >> 5, ntile = bid & 31;  // 256 x 32
  int tid = threadIdx.x, wv = tid >> 6, ln = tid & 63;

  int xrow[4];
#pragma unroll
  for (int i = 0; i < 4; ++i) {
    int chunk = wv * 4 + i;
    int r = chunk * 8 + (ln >> 3);
    xrow[i] = x[mtile * 128 + r];
  }

  auto stage = [&](int buf, int kb) {
    int k0 = kb * 64;
#pragma unroll
    for (int i = 0; i < 4; ++i) {
      int chunk = wv * 4 + i;
      int r = chunk * 8 + (ln >> 3);
      const unsigned short* srcA =
          emb_bf + (size_t)xrow[i] * 512 + k0 + (((ln & 7) ^ (r & 7)) << 3);
      gload_lds16(srcA, &A_lds[buf][chunk * 512]);
      const unsigned short* srcB =
          W_sw + (size_t)(ntile * 128 + r) * 512 + k0 + ((ln & 7) << 3);
      gload_lds16(srcB, &B_lds[buf][chunk * 512]);
    }
  };

  f32x4 acc[4][4];
#pragma unroll
  for (int i = 0; i < 4; ++i)
#pragma unroll
    for (int j = 0; j < 4; ++j) acc[i][j] = (f32x4)0.0f;

  int wm = wv >> 1, wn = wv & 1;
  stage(0, 0);
#pragma unroll 1
  for (int kb = 0; kb < 8; ++kb) {
    __syncthreads();
    if (kb < 7) stage((kb + 1) & 1, kb + 1);
    int buf = kb & 1;
#pragma unroll
    for (int ks = 0; ks < 2; ++ks) {
      bf16x8 a[4], b[4];
#pragma unroll
      for (int f = 0; f < 4; ++f) {
        int r = wm * 64 + f * 16 + (ln & 15);
        int sa = ((ks * 4 + (ln >> 4)) ^ (r & 7)) & 7;
        a[f] = *(const bf16x8*)&A_lds[buf][r * 64 + sa * 8];
        int n = wn * 64 + f * 16 + (ln & 15);
        int sb = ((ks * 4 + (ln >> 4)) ^ (n & 7)) & 7;
        b[f] = *(const bf16x8*)&B_lds[buf][n * 64 + sb * 8];
      }
#pragma unroll
      for (int i = 0; i < 4; ++i)
#pragma unroll
        for (int j = 0; j < 4; ++j)
          acc[i][j] = __builtin_amdgcn_mfma_f32_16x16x32_bf16(a[i], b[j], acc[i][j], 0, 0, 0);
    }
  }
#pragma unroll
  for (int fm = 0; fm < 4; ++fm) {
#pragma unroll
    for (int fn = 0; fn < 4; ++fn) {
      int n = ntile * 128 + wn * 64 + fn * 16 + (ln & 15);
      float bn = bias[n];
      int m0 = mtile * 128 + wm * 64 + fm * 16 + ((ln >> 4) << 2);
#pragma unroll
      for (int i = 0; i < 4; ++i) {
        pre[(size_t)(m0 + i) * 4096 + n] = f2bf(acc[fm][fn][i] + bn);
      }
    }
  }
}

// ---------------- flag init (256 flags, each on its own 64B line) ----------------
__global__ void init_flags(unsigned int* f) {
  int i = blockIdx.x * blockDim.x + threadIdx.x;  // 4096 dwords = 16 KB
  __hip_atomic_store(&f[i], 0u, __ATOMIC_RELAXED, __HIP_MEMORY_SCOPE_AGENT);
}

// ---------------- persistent LSTM recurrence ----------------
// grid 256 = 4 batch-groups (32 rows) x 64 j-slices (16 hidden cols); 512 thr = 8 waves.
// EXACT r7 protocol (proven: flags + explicit per-thread vmcnt(0) release drain +
// SYNC2; fine-grained per-wave consume of 8 producer flags; dedicated agent-only
// hbc/flags regions) with ONE delta:
//   FLAG LINE SPREADING: flag[js] lives at dword offset (bg*64+js)*16 -> one 64B
//   MALL line per flag. Theory: 512 waves/bg continuously agent-polling 64 flags
//   packed in 4 lines serialize at the coherence point, inflating poll-detect
//   latency to multiple RTs; one-flag-per-line cuts per-line pollers ~8x.
__global__ __launch_bounds__(512, 2) void lstm_kernel(
    const unsigned short* __restrict__ pre, const unsigned short* __restrict__ U_t,
    unsigned short* __restrict__ hbc, float* __restrict__ out, unsigned int* flags) {
  __shared__ float zbuf[8][32][68];  // [wave slice][row][z-col], padded
  int bid = blockIdx.x;
  int bg = bid >> 6, js = bid & 63;
  int tid = threadIdx.x, wv = tid >> 6, ln = tid & 63;

  // resident B fragments: ub[gate][kk]; col = gate*1024 + js*16 + (ln&15)
  bf16x8 ub[4][4];
#pragma unroll
  for (int f = 0; f < 4; ++f) {
    int col = f * 1024 + js * 16 + (ln & 15);
#pragma unroll
    for (int kk = 0; kk < 4; ++kk) {
      int k = wv * 128 + kk * 32 + ((ln >> 4) << 3);
      ub[f][kk] = *(const bf16x8*)&U_t[(size_t)col * 1024 + k];
    }
  }

  // gate-phase ownership: 512 threads = 32 rows x 16 j
  int row = tid >> 4, j = tid & 15;
  int b = bg * 32 + row;
  int hcol = js * 16 + j;
  float c_state = 0.0f;
  size_t preb = ((size_t)b * 256) * 4096 + (size_t)(js * 16 + j);
  size_t outb = ((size_t)b * 256) * 1024 + (size_t)hcol;
  int arow0 = bg * 32 + (ln & 15);
  int arow1 = arow0 + 16;
  // one flag per 64B line: dword index = (bg*64 + js) * 16
  const unsigned int* flp = flags + ((bg * 64 + (wv << 3) + (ln & 7)) << 4);
  unsigned int* myflag = flags + ((bg * 64 + js) << 4);

  // prefetch pre[t=0]
  float z0n, z1n, z2n, z3n;
  {
    const unsigned short* pp = pre + preb;
    z0n = bf2f(pp[0]); z1n = bf2f(pp[1024]); z2n = bf2f(pp[2048]); z3n = bf2f(pp[3072]);
  }

#pragma unroll 1
  for (int t = 0; t < 256; ++t) {
    int p = t & 1;
    if (t > 0) {
      // per-wave: wait only for this wave's 8 producer WGs to publish h_{t-1}
      int guard = 0;
      while (!__all((int)(__hip_atomic_load(flp, __ATOMIC_RELAXED,
                                            __HIP_MEMORY_SCOPE_AGENT) >= (unsigned)t))) {
        if (++guard > 4000000) break;  // watchdog: fail fast+visibly, never hang
        __builtin_amdgcn_s_sleep(1);
      }
      // compiler memory barrier: h loads below must NOT be hoisted above the poll
      asm volatile("" ::: "memory");
      const unsigned short* hprev = hbc + (size_t)(p ^ 1) * 131072;
      f32x4 acc[2][4];
#pragma unroll
      for (int m = 0; m < 2; ++m)
#pragma unroll
        for (int f = 0; f < 4; ++f) acc[m][f] = (f32x4)0.0f;
#pragma unroll
      for (int kk = 0; kk < 4; ++kk) {
        int k = wv * 128 + kk * 32 + ((ln >> 4) << 3);
        bf16x8 a0 = loadh16(&hprev[(size_t)arow0 * 1024 + k]);
        bf16x8 a1 = loadh16(&hprev[(size_t)arow1 * 1024 + k]);
#pragma unroll
        for (int f = 0; f < 4; ++f) {
          acc[0][f] = __builtin_amdgcn_mfma_f32_16x16x32_bf16(a0, ub[f][kk], acc[0][f], 0, 0, 0);
          acc[1][f] = __builtin_amdgcn_mfma_f32_16x16x32_bf16(a1, ub[f][kk], acc[1][f], 0, 0, 0);
        }
      }
      // private-slice zbuf writes (2-way bank alias max)
#pragma unroll
      for (int m = 0; m < 2; ++m)
#pragma unroll
        for (int f = 0; f < 4; ++f)
#pragma unroll
          for (int i = 0; i < 4; ++i)
            zbuf[wv][m * 16 + ((ln >> 4) << 2) + i][f * 16 + (ln & 15)] = acc[m][f][i];
      __syncthreads();  // SYNC1: all z slices visible; joins all waves' polls
    }
    // gates (Keras order i,f,c,o) from prefetched pre values
    float z0 = z0n, z1 = z1n, z2 = z2n, z3 = z3n;
    if (t > 0) {
      float s0 = 0.f, s1 = 0.f, s2 = 0.f, s3 = 0.f;
#pragma unroll
      for (int s = 0; s < 8; ++s) {
        s0 += zbuf[s][row][j];
        s1 += zbuf[s][row][16 + j];
        s2 += zbuf[s][row][32 + j];
        s3 += zbuf[s][row][48 + j];
      }
      z0 += s0; z1 += s1; z2 += s2; z3 += s3;
    }
    float ig = sigm(z0), fg = sigm(z1), gg = tanh_f(z2), og = sigm(z3);
    c_state = fg * c_state + ig * gg;
    float h = og * tanh_f(c_state);
    // device-coherent h publish (write-through to the coherence point)
    __hip_atomic_store(&hbc[(size_t)p * 131072 + (size_t)b * 1024 + hcol], f2bf(h),
                       __ATOMIC_RELAXED, __HIP_MEMORY_SCOPE_AGENT);
    if (t == 255) {
      out[outb + (size_t)t * 1024] = h;
      out[33554432 + (size_t)b * 1024 + hcol] = h;
      out[33554432 + 131072 + (size_t)b * 1024 + hcol] = c_state;
    } else {
      // EXPLICIT release drain: every wave waits for its own h-store to reach the
      // coherence point BEFORE the barrier; the flag store after the barrier is then
      // ordered after ALL waves' h-stores. Also orders zbuf reads(t) vs writes(t+1).
      asm volatile("s_waitcnt vmcnt(0)" ::: "memory");
      __syncthreads();  // SYNC2
      if (tid == 0)
        __hip_atomic_store(myflag, (unsigned)(t + 1), __ATOMIC_RELAXED,
                           __HIP_MEMORY_SCOPE_AGENT);
      // bulk out store + next-step prefetch AFTER the publish: off the release path,
      // latency hides under the next poll phase.
      out[outb + (size_t)t * 1024] = h;
      const unsigned short* pp = pre + preb + (size_t)(t + 1) * 4096;
      z0n = bf2f(pp[0]); z1n = bf2f(pp[1024]); z2n = bf2f(pp[2048]); z3n = bf2f(pp[3072]);
    }
  }
}

// ---------------- launcher ----------------
extern "C" void kernel_launch(void* const* d_in, const int* in_sizes, int n_in,
                              void* d_out, int out_size, void* d_ws, size_t ws_size,
                              hipStream_t stream) {
  const int*   x    = (const int*)d_in[0];
  // d_in[1] = hidden (ignored by reference module)
  const float* emb  = (const float*)d_in[2];
  const float* W    = (const float*)d_in[3];
  const float* U    = (const float*)d_in[4];
  const float* bias = (const float*)d_in[5];
  float* out = (float*)d_out;

  // workspace layout (bytes) -- r7 layout, flags widened to one 64B line per flag
  const size_t OFS_PRE = 0;                     // 32768*4096*2 = 268435456
  const size_t OFS_EMB = 268435456;             // 32000*512*2  = 32768000
  const size_t OFS_WSW = 301203456;             // 4096*512*2   = 4194304
  const size_t OFS_UT  = 305397760;             // 4096*1024*2  = 8388608
  const size_t OFS_HBC = 313786368;             // 2*128*1024*2 = 524288
  const size_t OFS_FLG = 314310656;             // 256 * 64B    = 16384
  const size_t WS_NEED = 314327040;
  if (ws_size < WS_NEED) return;  // insufficient scratch -> fail validation visibly

  char* ws = (char*)d_ws;
  unsigned short* pre_p = (unsigned short*)(ws + OFS_PRE);
  unsigned short* emb_p = (unsigned short*)(ws + OFS_EMB);
  unsigned short* wsw_p = (unsigned short*)(ws + OFS_WSW);
  unsigned short* ut_p  = (unsigned short*)(ws + OFS_UT);
  unsigned short* hbc_p = (unsigned short*)(ws + OFS_HBC);
  unsigned int*   flg_p = (unsigned int*)(ws + OFS_FLG);

  cvt_bf16_vec<<<2048, 256, 0, stream>>>((const float4*)emb, (ushort4*)emb_p, 4096000);
  transpose_cvt<1><<<dim3(8, 64), 256, 0, stream>>>(W, wsw_p, 512, 4096);
  transpose_cvt<0><<<dim3(16, 64), 256, 0, stream>>>(U, ut_p, 1024, 4096);
  init_flags<<<16, 256, 0, stream>>>(flg_p);
  pregemm<<<8192, 256, 0, stream>>>(emb_p, x, wsw_p, bias, pre_p);

  const unsigned short* pre_c = pre_p;
  const unsigned short* ut_c  = ut_p;
  unsigned short* hbc_v = hbc_p;
  float* out_v = out;
  unsigned int* flg_v = flg_p;
  void* args[] = {(void*)&pre_c, (void*)&ut_c, (void*)&hbc_v, (void*)&out_v, (void*)&flg_v};
  hipLaunchCooperativeKernel((const void*)lstm_kernel, dim3(256), dim3(512), args, 0, stream);
}

// Round 11
// 1343.623 us; speedup vs baseline: 1.9981x; 1.3388x over previous
//
#include <hip/hip_runtime.h>

typedef __attribute__((ext_vector_type(8))) short bf16x8;
typedef __attribute__((ext_vector_type(4))) float f32x4;

// ---- sizes ----
// B=128, T=256, EMB=512, H=1024, 4H=4096, VOC=32000
// out layout: [128][256][1024] f32, then hT [128][1024], then cT [128][1024]

__device__ __forceinline__ unsigned short f2bf(float f) {
  unsigned int u = __builtin_bit_cast(unsigned int, f);
  u = (u + 0x7FFFu + ((u >> 16) & 1u)) >> 16;  // RNE
  return (unsigned short)u;
}
__device__ __forceinline__ float bf2f(unsigned short s) {
  unsigned int u = ((unsigned int)s) << 16;
  return __builtin_bit_cast(float, u);
}
__device__ __forceinline__ void gload_lds16(const void* g, void* l) {
  __builtin_amdgcn_global_load_lds(
      (const __attribute__((address_space(1))) void*)g,
      (__attribute__((address_space(3))) void*)l, 16, 0, 0);
}
__device__ __forceinline__ float sigm(float x) { return 1.0f / (1.0f + __expf(-x)); }
__device__ __forceinline__ float tanh_f(float x) {
  float e = __expf(2.0f * x);
  return 1.0f - 2.0f / (e + 1.0f);  // saturates correctly, no NaN at +-inf
}

// device-coherent (agent-scope) 16B h load as two 8B atomic loads
__device__ __forceinline__ bf16x8 loadh16(const unsigned short* p) {
  unsigned long long* q = (unsigned long long*)p;
  unsigned long long lo = __hip_atomic_load(q, __ATOMIC_RELAXED, __HIP_MEMORY_SCOPE_AGENT);
  unsigned long long hi = __hip_atomic_load(q + 1, __ATOMIC_RELAXED, __HIP_MEMORY_SCOPE_AGENT);
  union { unsigned long long u[2]; bf16x8 v; } c;
  c.u[0] = lo; c.u[1] = hi;
  return c.v;
}

// ---------------- f32 -> bf16 elementwise (emb table) ----------------
__global__ void cvt_bf16_vec(const float4* __restrict__ in, ushort4* __restrict__ out, int n4) {
  int i = blockIdx.x * blockDim.x + threadIdx.x;
  int stride = gridDim.x * blockDim.x;
  for (; i < n4; i += stride) {
    float4 v = in[i];
    ushort4 o;
    o.x = f2bf(v.x); o.y = f2bf(v.y); o.z = f2bf(v.z); o.w = f2bf(v.w);
    out[i] = o;
  }
}

// ---- transpose f32 [K][N] -> bf16 [N][K]; SWZ: bake 16B-slot XOR swizzle ----
template <int SWZ>
__global__ void transpose_cvt(const float* __restrict__ in, unsigned short* __restrict__ out,
                              int K, int N) {
  __shared__ float tile[64][65];
  int k0 = blockIdx.x * 64, n0 = blockIdx.y * 64;
  int tid = threadIdx.x;
  int c = tid & 63, rq = tid >> 6;
#pragma unroll
  for (int rr = 0; rr < 16; ++rr) {
    int r = rr * 4 + rq;
    tile[r][c] = in[(size_t)(k0 + r) * N + n0 + c];
  }
  __syncthreads();
#pragma unroll
  for (int ww = 0; ww < 16; ++ww) {
    int nl = ww * 4 + rq;
    int n = n0 + nl;
    int kd = c;
    int ksrc;
    if (SWZ) {
      int s = kd >> 3, e = kd & 7;
      ksrc = ((((s ^ (n & 7)) & 7)) << 3) | e;
    } else {
      ksrc = kd;
    }
    out[(size_t)n * K + k0 + kd] = f2bf(tile[ksrc][nl]);
  }
}

// ---------------- pre = gather(emb,x) @ W + b   -> bf16 [32768][4096] ----------------
__global__ __launch_bounds__(256) void pregemm(
    const unsigned short* __restrict__ emb_bf, const int* __restrict__ x,
    const unsigned short* __restrict__ W_sw, const float* __restrict__ bias,
    unsigned short* __restrict__ pre) {
  __shared__ __align__(16) unsigned short A_lds[2][8192];  // 128 rows x 64 k (swizzled slots)
  __shared__ __align__(16) unsigned short B_lds[2][8192];
  int bid = blockIdx.x;
  int mtile = bid >> 5, ntile = bid & 31;  // 256 x 32
  int tid = threadIdx.x, wv = tid >> 6, ln = tid & 63;

  int xrow[4];
#pragma unroll
  for (int i = 0; i < 4; ++i) {
    int chunk = wv * 4 + i;
    int r = chunk * 8 + (ln >> 3);
    xrow[i] = x[mtile * 128 + r];
  }

  auto stage = [&](int buf, int kb) {
    int k0 = kb * 64;
#pragma unroll
    for (int i = 0; i < 4; ++i) {
      int chunk = wv * 4 + i;
      int r = chunk * 8 + (ln >> 3);
      const unsigned short* srcA =
          emb_bf + (size_t)xrow[i] * 512 + k0 + (((ln & 7) ^ (r & 7)) << 3);
      gload_lds16(srcA, &A_lds[buf][chunk * 512]);
      const unsigned short* srcB =
          W_sw + (size_t)(ntile * 128 + r) * 512 + k0 + ((ln & 7) << 3);
      gload_lds16(srcB, &B_lds[buf][chunk * 512]);
    }
  };

  f32x4 acc[4][4];
#pragma unroll
  for (int i = 0; i < 4; ++i)
#pragma unroll
    for (int j = 0; j < 4; ++j) acc[i][j] = (f32x4)0.0f;

  int wm = wv >> 1, wn = wv & 1;
  stage(0, 0);
#pragma unroll 1
  for (int kb = 0; kb < 8; ++kb) {
    __syncthreads();
    if (kb < 7) stage((kb + 1) & 1, kb + 1);
    int buf = kb & 1;
#pragma unroll
    for (int ks = 0; ks < 2; ++ks) {
      bf16x8 a[4], b[4];
#pragma unroll
      for (int f = 0; f < 4; ++f) {
        int r = wm * 64 + f * 16 + (ln & 15);
        int sa = ((ks * 4 + (ln >> 4)) ^ (r & 7)) & 7;
        a[f] = *(const bf16x8*)&A_lds[buf][r * 64 + sa * 8];
        int n = wn * 64 + f * 16 + (ln & 15);
        int sb = ((ks * 4 + (ln >> 4)) ^ (n & 7)) & 7;
        b[f] = *(const bf16x8*)&B_lds[buf][n * 64 + sb * 8];
      }
#pragma unroll
      for (int i = 0; i < 4; ++i)
#pragma unroll
        for (int j = 0; j < 4; ++j)
          acc[i][j] = __builtin_amdgcn_mfma_f32_16x16x32_bf16(a[i], b[j], acc[i][j], 0, 0, 0);
    }
  }
#pragma unroll
  for (int fm = 0; fm < 4; ++fm) {
#pragma unroll
    for (int fn = 0; fn < 4; ++fn) {
      int n = ntile * 128 + wn * 64 + fn * 16 + (ln & 15);
      float bn = bias[n];
      int m0 = mtile * 128 + wm * 64 + fm * 16 + ((ln >> 4) << 2);
#pragma unroll
      for (int i = 0; i < 4; ++i) {
        pre[(size_t)(m0 + i) * 4096 + n] = f2bf(acc[fm][fn][i] + bn);
      }
    }
  }
}

// ---------------- flag init (256 flags, each on its own 64B line) ----------------
__global__ void init_flags(unsigned int* f) {
  int i = blockIdx.x * blockDim.x + threadIdx.x;  // 4096 dwords = 16 KB
  __hip_atomic_store(&f[i], 0u, __ATOMIC_RELAXED, __HIP_MEMORY_SCOPE_AGENT);
}

// ---------------- persistent LSTM recurrence ----------------
// grid 256 = 8 batch-groups (16 rows) x 32 j-slices (32 hidden cols); 512 thr = 8 waves.
// Protocol identical to r10 (proven): per-wave fine poll of producer flags (line-spread),
// explicit per-thread vmcnt(0) release drain + barrier, tid0 per-WG flag, agent-scope
// h exchange in a dedicated region. Deltas vs r10:
//  (1) 16-row batch-groups: per-WG all-to-all h read = 16 rows x 2KB = 32KB (was 64KB)
//      -> MALL read volume halves (8 MB/step). Wave k-partition [128wv,+128) and kk
//      order unchanged -> z bit-identical to r7/r10.
//  (2) packed h publish: h -> 1KB LDS buffer -> 128 threads store 8B each (was 512x2B)
//      -> 4x fewer MALL write transactions, faster drain. Costs one extra barrier.
// Soundness: SYNC1(t) joins 8 waves x 4 distinct producer flags = all 32 producers of
// the bg at >= t; WG's h_t stores follow; a consumer's flag(t+2) follows its h_t reads;
// producer overwrites h_t's parity slot (at t+2) only after SYNC1(t+2) => all flags
// >= t+2 => all h_t reads done. zbuf WAR: reads(t) precede SYNC2a(t); writes(t+1)
// follow SYNC2b(t). Sound.
__global__ __launch_bounds__(512, 2) void lstm_kernel(
    const unsigned short* __restrict__ pre, const unsigned short* __restrict__ U_t,
    unsigned short* __restrict__ hbc, float* __restrict__ out, unsigned int* flags) {
  __shared__ float zbuf[8][16][132];      // [wave slice][row][z-col], padded (67.6 KB)
  __shared__ unsigned short hpack[512];   // 16 rows x 32 cols packed h (1 KB)
  int bid = blockIdx.x;
  int bg = bid >> 5, js = bid & 31;
  int tid = threadIdx.x, wv = tid >> 6, ln = tid & 63;

  // resident B fragments: ub[gate][kk][cg]; col = gate*1024 + js*32 + cg*16 + (ln&15)
  bf16x8 ub[4][4][2];
#pragma unroll
  for (int g = 0; g < 4; ++g)
#pragma unroll
    for (int kk = 0; kk < 4; ++kk)
#pragma unroll
      for (int cg = 0; cg < 2; ++cg) {
        int col = g * 1024 + js * 32 + cg * 16 + (ln & 15);
        int k = wv * 128 + kk * 32 + ((ln >> 4) << 3);
        ub[g][kk][cg] = *(const bf16x8*)&U_t[(size_t)col * 1024 + k];
      }

  // gate-phase ownership: 512 threads = 16 rows x 32 j
  int row = tid >> 5, j = tid & 31;
  int b = bg * 16 + row;
  int hcol = js * 32 + j;
  float c_state = 0.0f;
  size_t preb = ((size_t)b * 256) * 4096 + (size_t)(js * 32 + j);  // + g*1024 per gate
  size_t outb = ((size_t)b * 256) * 1024 + (size_t)hcol;
  int arow = bg * 16 + (ln & 15);
  // one flag per 64B line; consumer wave wv's producers: js' in {4wv..4wv+3}
  const unsigned int* flp = flags + ((bg * 32 + (wv << 2) + (ln & 3)) << 4);
  unsigned int* myflag = flags + ((bg * 32 + js) << 4);
  // packed publish: threads 0..127 store 8B = 4 cols of one row
  int srow = tid >> 3, sseg = tid & 7;
  size_t hstb = (size_t)(bg * 16 + srow) * 1024 + (size_t)(js * 32 + sseg * 4);

  // prefetch pre[t=0]
  float z0n, z1n, z2n, z3n;
  {
    const unsigned short* pp = pre + preb;
    z0n = bf2f(pp[0]); z1n = bf2f(pp[1024]); z2n = bf2f(pp[2048]); z3n = bf2f(pp[3072]);
  }

#pragma unroll 1
  for (int t = 0; t < 256; ++t) {
    int p = t & 1;
    if (t > 0) {
      // per-wave: wait for this wave's 4 producer WGs to publish h_{t-1}
      int guard = 0;
      while (!__all((int)(__hip_atomic_load(flp, __ATOMIC_RELAXED,
                                            __HIP_MEMORY_SCOPE_AGENT) >= (unsigned)t))) {
        if (++guard > 4000000) break;  // watchdog: fail fast+visibly, never hang
        __builtin_amdgcn_s_sleep(1);
      }
      // compiler memory barrier: h loads below must NOT be hoisted above the poll
      asm volatile("" ::: "memory");
      const unsigned short* hprev = hbc + (size_t)(p ^ 1) * 131072;
      f32x4 acc[4][2];
#pragma unroll
      for (int g = 0; g < 4; ++g)
#pragma unroll
        for (int cg = 0; cg < 2; ++cg) acc[g][cg] = (f32x4)0.0f;
#pragma unroll
      for (int kk = 0; kk < 4; ++kk) {
        int k = wv * 128 + kk * 32 + ((ln >> 4) << 3);
        bf16x8 a = loadh16(&hprev[(size_t)arow * 1024 + k]);
#pragma unroll
        for (int g = 0; g < 4; ++g)
#pragma unroll
          for (int cg = 0; cg < 2; ++cg)
            acc[g][cg] = __builtin_amdgcn_mfma_f32_16x16x32_bf16(a, ub[g][kk][cg],
                                                                 acc[g][cg], 0, 0, 0);
      }
      // private-slice zbuf writes (2-way bank alias max)
#pragma unroll
      for (int g = 0; g < 4; ++g)
#pragma unroll
        for (int cg = 0; cg < 2; ++cg)
#pragma unroll
          for (int i = 0; i < 4; ++i)
            zbuf[wv][((ln >> 4) << 2) + i][g * 32 + cg * 16 + (ln & 15)] = acc[g][cg][i];
      __syncthreads();  // SYNC1: all z slices visible; joins all waves' polls
    }
    // gates (Keras order i,f,c,o) from prefetched pre values
    float z0 = z0n, z1 = z1n, z2 = z2n, z3 = z3n;
    if (t > 0) {
      float s0 = 0.f, s1 = 0.f, s2 = 0.f, s3 = 0.f;
#pragma unroll
      for (int s = 0; s < 8; ++s) {
        s0 += zbuf[s][row][j];
        s1 += zbuf[s][row][32 + j];
        s2 += zbuf[s][row][64 + j];
        s3 += zbuf[s][row][96 + j];
      }
      z0 += s0; z1 += s1; z2 += s2; z3 += s3;
    }
    float ig = sigm(z0), fg = sigm(z1), gg = tanh_f(z2), og = sigm(z3);
    c_state = fg * c_state + ig * gg;
    float h = og * tanh_f(c_state);
    if (t == 255) {
      out[outb + (size_t)t * 1024] = h;
      out[33554432 + (size_t)b * 1024 + hcol] = h;
      out[33554432 + 131072 + (size_t)b * 1024 + hcol] = c_state;
    } else {
      // packed publish: h -> LDS, then 128 threads issue 8B agent stores
      hpack[row * 32 + j] = f2bf(h);
      __syncthreads();  // SYNC2a: hpack complete (also after all zbuf reads)
      if (tid < 128) {
        unsigned long long v = ((const unsigned long long*)hpack)[tid];
        __hip_atomic_store((unsigned long long*)&hbc[(size_t)p * 131072 + hstb], v,
                           __ATOMIC_RELAXED, __HIP_MEMORY_SCOPE_AGENT);
      }
      // EXPLICIT release drain: storing threads' h-stores reach the coherence point
      // BEFORE the barrier; flag store after the barrier is ordered after them.
      asm volatile("s_waitcnt vmcnt(0)" ::: "memory");
      __syncthreads();  // SYNC2b
      if (tid == 0)
        __hip_atomic_store(myflag, (unsigned)(t + 1), __ATOMIC_RELAXED,
                           __HIP_MEMORY_SCOPE_AGENT);
      // bulk out store + next-step prefetch AFTER the publish: off the release path
      out[outb + (size_t)t * 1024] = h;
      const unsigned short* pp = pre + preb + (size_t)(t + 1) * 4096;
      z0n = bf2f(pp[0]); z1n = bf2f(pp[1024]); z2n = bf2f(pp[2048]); z3n = bf2f(pp[3072]);
    }
  }
}

// ---------------- launcher ----------------
extern "C" void kernel_launch(void* const* d_in, const int* in_sizes, int n_in,
                              void* d_out, int out_size, void* d_ws, size_t ws_size,
                              hipStream_t stream) {
  const int*   x    = (const int*)d_in[0];
  // d_in[1] = hidden (ignored by reference module)
  const float* emb  = (const float*)d_in[2];
  const float* W    = (const float*)d_in[3];
  const float* U    = (const float*)d_in[4];
  const float* bias = (const float*)d_in[5];
  float* out = (float*)d_out;

  // workspace layout (bytes) -- r10 layout (dedicated agent-only hbc/flags regions)
  const size_t OFS_PRE = 0;                     // 32768*4096*2 = 268435456
  const size_t OFS_EMB = 268435456;             // 32000*512*2  = 32768000
  const size_t OFS_WSW = 301203456;             // 4096*512*2   = 4194304
  const size_t OFS_UT  = 305397760;             // 4096*1024*2  = 8388608
  const size_t OFS_HBC = 313786368;             // 2*128*1024*2 = 524288
  const size_t OFS_FLG = 314310656;             // 256 * 64B    = 16384
  const size_t WS_NEED = 314327040;
  if (ws_size < WS_NEED) return;  // insufficient scratch -> fail validation visibly

  char* ws = (char*)d_ws;
  unsigned short* pre_p = (unsigned short*)(ws + OFS_PRE);
  unsigned short* emb_p = (unsigned short*)(ws + OFS_EMB);
  unsigned short* wsw_p = (unsigned short*)(ws + OFS_WSW);
  unsigned short* ut_p  = (unsigned short*)(ws + OFS_UT);
  unsigned short* hbc_p = (unsigned short*)(ws + OFS_HBC);
  unsigned int*   flg_p = (unsigned int*)(ws + OFS_FLG);

  cvt_bf16_vec<<<2048, 256, 0, stream>>>((const float4*)emb, (ushort4*)emb_p, 4096000);
  transpose_cvt<1><<<dim3(8, 64), 256, 0, stream>>>(W, wsw_p, 512, 4096);
  transpose_cvt<0><<<dim3(16, 64), 256, 0, stream>>>(U, ut_p, 1024, 4096);
  init_flags<<<16, 256, 0, stream>>>(flg_p);
  pregemm<<<8192, 256, 0, stream>>>(emb_p, x, wsw_p, bias, pre_p);

  const unsigned short* pre_c = pre_p;
  const unsigned short* ut_c  = ut_p;
  unsigned short* hbc_v = hbc_p;
  float* out_v = out;
  unsigned int* flg_v = flg_p;
  void* args[] = {(void*)&pre_c, (void*)&ut_c, (void*)&hbc_v, (void*)&out_v, (void*)&flg_v};
  hipLaunchCooperativeKernel((const void*)lstm_kernel, dim3(256), dim3(512), args, 0, stream);
}